// Round 5
// baseline (296.286 us; speedup 1.0000x reference)
//
#include <hip/hip_runtime.h>

#define NV 16384
#define JT 256            // floats per row-tile (1 KB = one gl_lds per row)
#define NT (NV / JT)      // 64 tiles
#define THREADS 256

typedef const __attribute__((address_space(1))) void* as1_ptr;
typedef __attribute__((address_space(3))) void* as3_ptr;

__device__ __forceinline__ void gload_lds16(const float* g, float* l) {
  __builtin_amdgcn_global_load_lds((as1_ptr)g, (as3_ptr)l, 16, 0, 0);
}

#define FENCE asm volatile("" ::: "memory")
#define WAITV(n) asm volatile("s_waitcnt vmcnt(" #n ")" ::: "memory")

__global__ __launch_bounds__(THREADS, 4) void lap_loss_kernel(
    const float* __restrict__ x, const float* __restrict__ L,
    float* __restrict__ out) {
  // Wave-PRIVATE double buffers: no inter-wave sharing -> no s_barrier.
  __shared__ float lbuf[4][2][4][JT];   // [wave][dbuf][row][j] = 32 KB
  __shared__ float red[4][4];           // [wave][batch] epilogue scratch

  const int lane = threadIdx.x & 63;
  const int w    = threadIdx.x >> 6;
  const size_t i0 = (size_t)blockIdx.x * 16 + (size_t)w * 4;  // wave's rows

  const float* gL0 = L + (i0 + 0) * NV + lane * 4;
  const float* gL1 = L + (i0 + 1) * NV + lane * 4;
  const float* gL2 = L + (i0 + 2) * NV + lane * 4;
  const float* gL3 = L + (i0 + 3) * NV + lane * 4;

  float acc[4][4][3];  // [row][batch][dim]
#pragma unroll
  for (int r = 0; r < 4; ++r)
#pragma unroll
    for (int b = 0; b < 4; ++b)
#pragma unroll
      for (int d = 0; d < 3; ++d) acc[r][b][d] = 0.f;

  // prologue: stage tile 0 into dbuf 0 (wave-private, 4 KB)
  gload_lds16(gL0, &lbuf[w][0][0][0]);
  gload_lds16(gL1, &lbuf[w][0][1][0]);
  gload_lds16(gL2, &lbuf[w][0][2][0]);
  gload_lds16(gL3, &lbuf[w][0][3][0]);

#pragma unroll 1
  for (int t = 0; t < NT; ++t) {
    const int cur = t & 1;
    const size_t jq = (size_t)(t * JT + lane * 4) * 3;  // lane's j-quad * 3

    // ---- x batches 0,1 (issued BEFORE next tile's gl_lds) ----
    const float4* xp0 = (const float4*)(x + 0 * (size_t)NV * 3 + jq);
    const float4* xp1 = (const float4*)(x + 1 * (size_t)NV * 3 + jq);
    float4 a0 = xp0[0], a1 = xp0[1], a2 = xp0[2];
    float4 b0 = xp1[0], b1 = xp1[1], b2 = xp1[2];
    FENCE;

    // ---- prefetch L(t+1) into the other private buffer ----
    if (t + 1 < NT) {
      gload_lds16(gL0 + (size_t)(t + 1) * JT, &lbuf[w][cur ^ 1][0][0]);
      gload_lds16(gL1 + (size_t)(t + 1) * JT, &lbuf[w][cur ^ 1][1][0]);
      gload_lds16(gL2 + (size_t)(t + 1) * JT, &lbuf[w][cur ^ 1][2][0]);
      gload_lds16(gL3 + (size_t)(t + 1) * JT, &lbuf[w][cur ^ 1][3][0]);
      WAITV(4);  // retire L(t) + x01; keep only L(t+1) in flight
    } else {
      WAITV(0);
    }

    // ---- this wave's 4 rows from its private LDS ----
    float4 lv0 = *(const float4*)&lbuf[w][cur][0][lane * 4];
    float4 lv1 = *(const float4*)&lbuf[w][cur][1][lane * 4];
    float4 lv2 = *(const float4*)&lbuf[w][cur][2][lane * 4];
    float4 lv3 = *(const float4*)&lbuf[w][cur][3][lane * 4];
    const float lf[4][4] = {{lv0.x, lv0.y, lv0.z, lv0.w},
                            {lv1.x, lv1.y, lv1.z, lv1.w},
                            {lv2.x, lv2.y, lv2.z, lv2.w},
                            {lv3.x, lv3.y, lv3.z, lv3.w}};

    {
      const float xa[12] = {a0.x, a0.y, a0.z, a0.w, a1.x, a1.y,
                            a1.z, a1.w, a2.x, a2.y, a2.z, a2.w};
      const float xb[12] = {b0.x, b0.y, b0.z, b0.w, b1.x, b1.y,
                            b1.z, b1.w, b2.x, b2.y, b2.z, b2.w};
#pragma unroll
      for (int r = 0; r < 4; ++r)
#pragma unroll
        for (int q = 0; q < 4; ++q)
#pragma unroll
          for (int d = 0; d < 3; ++d) {
            acc[r][0][d] = fmaf(lf[r][q], xa[q * 3 + d], acc[r][0][d]);
            acc[r][1][d] = fmaf(lf[r][q], xb[q * 3 + d], acc[r][1][d]);
          }
    }

    // ---- x batches 2,3 (younger than L(t+1): wait keeps prefetch alive) ----
    const float4* xp2 = (const float4*)(x + 2 * (size_t)NV * 3 + jq);
    const float4* xp3 = (const float4*)(x + 3 * (size_t)NV * 3 + jq);
    float4 c0 = xp2[0], c1 = xp2[1], c2 = xp2[2];
    float4 e0 = xp3[0], e1 = xp3[1], e2 = xp3[2];
    if (t + 1 < NT) { WAITV(4); } else { WAITV(0); }

    {
      const float xc[12] = {c0.x, c0.y, c0.z, c0.w, c1.x, c1.y,
                            c1.z, c1.w, c2.x, c2.y, c2.z, c2.w};
      const float xe[12] = {e0.x, e0.y, e0.z, e0.w, e1.x, e1.y,
                            e1.z, e1.w, e2.x, e2.y, e2.z, e2.w};
#pragma unroll
      for (int r = 0; r < 4; ++r)
#pragma unroll
        for (int q = 0; q < 4; ++q)
#pragma unroll
          for (int d = 0; d < 3; ++d) {
            acc[r][2][d] = fmaf(lf[r][q], xc[q * 3 + d], acc[r][2][d]);
            acc[r][3][d] = fmaf(lf[r][q], xe[q * 3 + d], acc[r][3][d]);
          }
    }
  }

  // ---- reduce: butterfly each (r,b,d) over 64 lanes, square, sum per b ----
  float s[4] = {0.f, 0.f, 0.f, 0.f};
#pragma unroll
  for (int r = 0; r < 4; ++r)
#pragma unroll
    for (int b = 0; b < 4; ++b)
#pragma unroll
      for (int d = 0; d < 3; ++d) {
        float v = acc[r][b][d];
#pragma unroll
        for (int off = 32; off > 0; off >>= 1)
          v += __shfl_xor(v, off, 64);
        s[b] += v * v;
      }

  if (lane == 0) {
#pragma unroll
    for (int b = 0; b < 4; ++b) red[w][b] = s[b];
  }
  __syncthreads();
  if (threadIdx.x < 4) {
    const int b = threadIdx.x;
    atomicAdd(&out[b], red[0][b] + red[1][b] + red[2][b] + red[3][b]);
  }
}

extern "C" void kernel_launch(void* const* d_in, const int* in_sizes, int n_in,
                              void* d_out, int out_size, void* d_ws, size_t ws_size,
                              hipStream_t stream) {
  const float* x = (const float*)d_in[0];
  const float* L = (const float*)d_in[1];
  float* out = (float*)d_out;

  // Harness poisons d_out with 0xAA and never re-poisons between replays.
  hipMemsetAsync(out, 0, out_size * sizeof(float), stream);

  const int nblocks = NV / 16;  // 1024 blocks = exactly 4 resident per CU
  lap_loss_kernel<<<nblocks, THREADS, 0, stream>>>(x, L, out);
}

// Round 6
// 230.626 us; speedup vs baseline: 1.2847x; 1.2847x over previous
//
#include <hip/hip_runtime.h>

#define NV 16384
#define BROWS 32          // L rows per block (R3 had 16; halves x re-read traffic)
#define JT 256            // j-tile width (floats); tile = 32 KB
#define NT (NV / JT)      // 64 tiles
#define THREADS 256

typedef const __attribute__((address_space(1))) void* as1_ptr;
typedef __attribute__((address_space(3))) void* as3_ptr;

__device__ __forceinline__ void gload_lds16(const float* g, float* l) {
  __builtin_amdgcn_global_load_lds((as1_ptr)g, (as3_ptr)l, 16, 0, 0);
}

#define FENCE asm volatile("" ::: "memory")
#define WAITV(n) asm volatile("s_waitcnt vmcnt(" #n ")" ::: "memory")

__global__ __launch_bounds__(THREADS, 2) void lap_loss_kernel(
    const float* __restrict__ x, const float* __restrict__ L,
    float* __restrict__ out) {
  __shared__ float lbuf[2][BROWS][JT];  // 2 x 32 KB double buffer

  const int lane = threadIdx.x & 63;
  const int w    = threadIdx.x >> 6;     // wave id == batch index b
  const size_t i0 = (size_t)blockIdx.x * BROWS;

  // wave w stages rows i0+8w .. i0+8w+7; lane covers 16B of each row
  const float* gL[8];
#pragma unroll
  for (int r = 0; r < 8; ++r)
    gL[r] = L + (i0 + 8 * w + r) * NV + lane * 4;

  // wave w's x stream: x[w][j][d], lane owns j-quad 4*lane (48B)
  const float* gx = x + (size_t)w * NV * 3 + lane * 12;

  float acc[BROWS][3];
#pragma unroll
  for (int r = 0; r < BROWS; ++r)
#pragma unroll
    for (int d = 0; d < 3; ++d) acc[r][d] = 0.f;

  // ---- prologue: x(0) loads, then the 8 gl_lds for tile 0 ----
  float4 xc0 = *(const float4*)(gx + 0);
  float4 xc1 = *(const float4*)(gx + 4);
  float4 xc2 = *(const float4*)(gx + 8);
  FENCE;
#pragma unroll
  for (int r = 0; r < 8; ++r)
    gload_lds16(gL[r], &lbuf[0][8 * w + r][0]);

#pragma unroll 1
  for (int t = 0; t < NT; ++t) {
    const int cur = t & 1;

    // 1) x(t+1) prefetch into regs — a FULL tile ahead of its use
    float4 xn0, xn1, xn2;
    if (t + 1 < NT) {
      const float* gxn = gx + (size_t)(t + 1) * JT * 3;
      xn0 = *(const float4*)(gxn + 0);
      xn1 = *(const float4*)(gxn + 4);
      xn2 = *(const float4*)(gxn + 8);
    }
    FENCE;

    // 2) gl_lds prefetch L(t+1) into the other buffer (8 newest vmem ops)
    if (t + 1 < NT) {
#pragma unroll
      for (int r = 0; r < 8; ++r)
        gload_lds16(gL[r] + (size_t)(t + 1) * JT, &lbuf[cur ^ 1][8 * w + r][0]);
      // retire L(t) + x(t+1); keep ONLY the 8 L(t+1) gl_lds in flight
      WAITV(8);
    } else {
      WAITV(0);
    }
    __builtin_amdgcn_s_barrier();
    FENCE;

    // 3) compute tile t: 32 rows x 12 FMAs per lane-j-quad, batch w
    {
      const float xf[12] = {xc0.x, xc0.y, xc0.z, xc0.w,
                            xc1.x, xc1.y, xc1.z, xc1.w,
                            xc2.x, xc2.y, xc2.z, xc2.w};
#pragma unroll
      for (int r = 0; r < BROWS; ++r) {
        float4 lv = *(const float4*)&lbuf[cur][r][lane * 4];
        const float lf[4] = {lv.x, lv.y, lv.z, lv.w};
#pragma unroll
        for (int jj = 0; jj < 4; ++jj)
#pragma unroll
          for (int d = 0; d < 3; ++d)
            acc[r][d] = fmaf(lf[jj], xf[jj * 3 + d], acc[r][d]);
      }
    }

    FENCE;
    __builtin_amdgcn_s_barrier();  // all waves done reading lbuf[cur]
    FENCE;

    xc0 = xn0; xc1 = xn1; xc2 = xn2;
  }

  // ---- butterfly-reduce each (row,d) partial over 64 lanes, square ----
  float s = 0.f;
#pragma unroll
  for (int r = 0; r < BROWS; ++r)
#pragma unroll
    for (int d = 0; d < 3; ++d) {
      float v = acc[r][d];
#pragma unroll
      for (int off = 32; off > 0; off >>= 1)
        v += __shfl_xor(v, off, 64);
      s += v * v;
    }

  if (lane == 0) atomicAdd(&out[w], s);  // wave w owns batch w
}

extern "C" void kernel_launch(void* const* d_in, const int* in_sizes, int n_in,
                              void* d_out, int out_size, void* d_ws, size_t ws_size,
                              hipStream_t stream) {
  const float* x = (const float*)d_in[0];
  const float* L = (const float*)d_in[1];
  float* out = (float*)d_out;

  // Harness poisons d_out with 0xAA and never re-poisons between replays.
  hipMemsetAsync(out, 0, out_size * sizeof(float), stream);

  const int nblocks = NV / BROWS;  // 512 blocks = exactly 2 resident per CU
  lap_loss_kernel<<<nblocks, THREADS, 0, stream>>>(x, L, out);
}

// Round 7
// 229.321 us; speedup vs baseline: 1.2920x; 1.0057x over previous
//
#include <hip/hip_runtime.h>

#define NV 16384
#define BROWS 32          // L rows per block
#define JT 256            // j-tile width (floats); tile = 32 KB
#define NT (NV / JT)      // 64 tiles
#define THREADS 256

typedef const __attribute__((address_space(1))) void* as1_ptr;
typedef __attribute__((address_space(3))) void* as3_ptr;

__device__ __forceinline__ void gload_lds16(const float* g, float* l) {
  __builtin_amdgcn_global_load_lds((as1_ptr)g, (as3_ptr)l, 16, 0, 0);
}

#define FENCE asm volatile("" ::: "memory")
#define WAITV(n) asm volatile("s_waitcnt vmcnt(" #n ")" ::: "memory")

__global__ __launch_bounds__(THREADS, 2) void lap_loss_kernel(
    const float* __restrict__ x, const float* __restrict__ L,
    float* __restrict__ out) {
  __shared__ float lbuf[2][BROWS][JT];  // 2 x 32 KB double buffer

  const int lane = threadIdx.x & 63;
  const int w    = threadIdx.x >> 6;     // wave id == batch index b
  const size_t i0 = (size_t)blockIdx.x * BROWS;

  // wave w stages rows i0+8w .. i0+8w+7; lane covers 16B of each row
  const float* gL[8];
#pragma unroll
  for (int r = 0; r < 8; ++r)
    gL[r] = L + (i0 + 8 * w + r) * NV + lane * 4;

  // wave w's x stream: x[w][j][d], lane owns j-quad 4*lane (48B)
  const float* gx = x + (size_t)w * NV * 3 + lane * 12;

  float acc[BROWS][3];
#pragma unroll
  for (int r = 0; r < BROWS; ++r)
#pragma unroll
    for (int d = 0; d < 3; ++d) acc[r][d] = 0.f;

  // ---- prologue: x(0) regs, then the 8 gl_lds for tile 0 ----
  float4 xc0 = *(const float4*)(gx + 0);
  float4 xc1 = *(const float4*)(gx + 4);
  float4 xc2 = *(const float4*)(gx + 8);
  FENCE;
#pragma unroll
  for (int r = 0; r < 8; ++r)
    gload_lds16(gL[r], &lbuf[0][8 * w + r][0]);
  FENCE;

#pragma unroll 1
  for (int t = 0; t < NT; ++t) {
    const int cur = t & 1;

    float4 xn0, xn1, xn2;
    if (t + 1 < NT) {
      // 1) gl_lds prefetch L(t+1) FIRST (older than the x prefetch)
#pragma unroll
      for (int r = 0; r < 8; ++r)
        gload_lds16(gL[r] + (size_t)(t + 1) * JT, &lbuf[cur ^ 1][8 * w + r][0]);
      FENCE;
      // 2) x(t+1) prefetch LAST -> youngest in the vmem queue
      const float* gxn = gx + (size_t)(t + 1) * JT * 3;
      xn0 = *(const float4*)(gxn + 0);
      xn1 = *(const float4*)(gxn + 4);
      xn2 = *(const float4*)(gxn + 8);
      FENCE;
      // 3) retire L(t)x8 + x(t)x3 (both one full tile old -> no stall);
      //    keep L(t+1)x8 + x(t+1)x3 = 11 in flight across barrier+compute
      WAITV(11);
    } else {
      WAITV(0);
    }
    __builtin_amdgcn_s_barrier();
    FENCE;

    // 4) compute tile t: 32 rows x 12 FMAs per lane-j-quad, batch w
    {
      const float xf[12] = {xc0.x, xc0.y, xc0.z, xc0.w,
                            xc1.x, xc1.y, xc1.z, xc1.w,
                            xc2.x, xc2.y, xc2.z, xc2.w};
#pragma unroll
      for (int r = 0; r < BROWS; ++r) {
        float4 lv = *(const float4*)&lbuf[cur][r][lane * 4];
        const float lf[4] = {lv.x, lv.y, lv.z, lv.w};
#pragma unroll
        for (int jj = 0; jj < 4; ++jj)
#pragma unroll
          for (int d = 0; d < 3; ++d)
            acc[r][d] = fmaf(lf[jj], xf[jj * 3 + d], acc[r][d]);
      }
    }

    FENCE;
    __builtin_amdgcn_s_barrier();  // all waves done reading lbuf[cur]
    FENCE;

    xc0 = xn0; xc1 = xn1; xc2 = xn2;
  }

  // ---- butterfly-reduce each (row,d) partial over 64 lanes, square ----
  float s = 0.f;
#pragma unroll
  for (int r = 0; r < BROWS; ++r)
#pragma unroll
    for (int d = 0; d < 3; ++d) {
      float v = acc[r][d];
#pragma unroll
      for (int off = 32; off > 0; off >>= 1)
        v += __shfl_xor(v, off, 64);
      s += v * v;
    }

  if (lane == 0) atomicAdd(&out[w], s);  // wave w owns batch w
}

extern "C" void kernel_launch(void* const* d_in, const int* in_sizes, int n_in,
                              void* d_out, int out_size, void* d_ws, size_t ws_size,
                              hipStream_t stream) {
  const float* x = (const float*)d_in[0];
  const float* L = (const float*)d_in[1];
  float* out = (float*)d_out;

  // Harness poisons d_out with 0xAA and never re-poisons between replays.
  hipMemsetAsync(out, 0, out_size * sizeof(float), stream);

  const int nblocks = NV / BROWS;  // 512 blocks = exactly 2 resident per CU
  lap_loss_kernel<<<nblocks, THREADS, 0, stream>>>(x, L, out);
}